// Round 1
// baseline (851.538 us; speedup 1.0000x reference)
//
#include <hip/hip_runtime.h>

#define HW   512
#define IMG  (HW*HW)       // 262144
#define NPAT 4096          // L = 64*64 patches
#define BATCH 4

// ws layout (float offsets)
#define OFF_C9   0          // 243 combined 9x9 weights + bc at [243]
#define OFF_W    256        // Wt[p][j] = (w2@w1)[j,p], 4096 floats
#define OFF_INI  4352       // ini_img [4][512][512]
#define OFF_FMAP (OFF_INI  + BATCH*IMG)
#define OFF_VIMG (OFF_FMAP + BATCH*IMG)
#define OFF_VFEA (OFF_VIMG + BATCH*IMG)

// ---------------- Kernel A: compose weights (tiny, 1 block) ----------------
__global__ __launch_bounds__(256) void k_compose(
    const float* __restrict__ w1img, const float* __restrict__ b1img,
    const float* __restrict__ w2img, const float* __restrict__ b2img,
    const float* __restrict__ w1,    const float* __restrict__ w2,
    float* __restrict__ ws) {
  int tid = threadIdx.x;
  // Wt[p][j] = sum_k w2[j,k]*w1[k,p]   (store transposed for conflict-free LDS reads later)
  for (int idx = tid; idx < 4096; idx += 256) {
    int p = idx >> 6, j = idx & 63;
    float acc = 0.f;
    for (int k = 0; k < 128; ++k) acc += w2[j*128 + k] * w1[k*64 + p];
    ws[OFF_W + p*64 + j] = acc;
  }
  // C9[i][dy][dx] = sum_m sum_{k2} w2img[m,k2] * w1img[m,i,d-k2]
  for (int idx = tid; idx < 243; idx += 256) {
    int i = idx / 81, r = idx % 81, dy = r / 9, dx = r % 9;
    float acc = 0.f;
    for (int m = 0; m < 64; ++m)
      for (int ky = 0; ky < 3; ++ky) {
        int k1y = dy - ky; if (k1y < 0 || k1y > 6) continue;
        for (int kx = 0; kx < 3; ++kx) {
          int k1x = dx - kx; if (k1x < 0 || k1x > 6) continue;
          acc += w2img[m*9 + ky*3 + kx] * w1img[(m*3 + i)*49 + k1y*7 + k1x];
        }
      }
    ws[OFF_C9 + idx] = acc;
  }
  if (tid == 0) {
    float acc = b2img[0];
    for (int m = 0; m < 64; ++m) {
      float s = 0.f;
      for (int k = 0; k < 9; ++k) s += w2img[m*9 + k];
      acc += b1img[m] * s;
    }
    ws[OFF_C9 + 243] = acc;
  }
}

// ---------------- Kernel B1: composite 9x9 conv ----------------
__global__ __launch_bounds__(256) void k_conv9(const float* __restrict__ x,
                                               const float* __restrict__ ws,
                                               float* __restrict__ ini) {
  __shared__ float sIn[3][24][24];
  __shared__ float sC[244];
  int bid = blockIdx.x;
  int b = bid >> 10;
  int t = bid & 1023;
  int ty0 = (t >> 5) << 4, tx0 = (t & 31) << 4;
  int tid = threadIdx.x;
  if (tid < 244) sC[tid] = ws[OFF_C9 + tid];
  for (int idx = tid; idx < 3*24*24; idx += 256) {
    int c = idx / 576, rr = (idx % 576) / 24, cc = idx % 24;
    int gy = ty0 + rr - 4, gx = tx0 + cc - 4;
    float v = 0.f;
    if ((unsigned)gy < 512u && (unsigned)gx < 512u)
      v = x[(b*3 + c)*IMG + gy*512 + gx];
    sIn[c][rr][cc] = v;
  }
  __syncthreads();
  int ty = tid >> 4, tx = tid & 15;
  float acc = sC[243];
  #pragma unroll
  for (int i = 0; i < 3; ++i)
    for (int dy = 0; dy < 9; ++dy)
      #pragma unroll
      for (int dx = 0; dx < 9; ++dx)
        acc += sC[i*81 + dy*9 + dx] * sIn[i][ty + dy][tx + dx];
  ini[b*IMG + (ty0 + ty)*512 + tx0 + tx] = acc;
}

// ---------------- Kernel B1b: border-ring correction ----------------
// Composite conv pads x; real conv2 zero-pads y1. Subtract the out-of-range
// y1 contributions on the 1-pixel output ring. One wave (64 lanes = 64 m) per pixel.
__global__ __launch_bounds__(256) void k_ring(const float* __restrict__ x,
                                              const float* __restrict__ w1img,
                                              const float* __restrict__ b1img,
                                              const float* __restrict__ w2img,
                                              float* __restrict__ ini) {
  int wid = blockIdx.x * 4 + (threadIdx.x >> 6);
  int lane = threadIdx.x & 63;
  int b = wid / 2044;
  int r = wid % 2044;
  int py, px;
  if (r < 512)       { py = 0;            px = r;        }
  else if (r < 1024) { py = 511;          px = r - 512;  }
  else if (r < 1534) { py = r - 1024 + 1; px = 0;        }
  else               { py = r - 1534 + 1; px = 511;      }
  int m = lane;
  float corr = 0.f;
  for (int k2y = 0; k2y < 3; ++k2y) {
    int qy = py + k2y - 1;
    for (int k2x = 0; k2x < 3; ++k2x) {
      int qx = px + k2x - 1;
      if (!(qy < 0 || qy >= 512 || qx < 0 || qx >= 512)) continue;  // only oob y1 positions
      float y1v = b1img[m];
      for (int i = 0; i < 3; ++i)
        for (int k1y = 0; k1y < 7; ++k1y) {
          int xy = qy + k1y - 3;
          if (xy < 0 || xy >= 512) continue;
          for (int k1x = 0; k1x < 7; ++k1x) {
            int xx = qx + k1x - 3;
            if (xx < 0 || xx >= 512) continue;
            y1v += w1img[(m*3 + i)*49 + k1y*7 + k1x] * x[(b*3 + i)*IMG + xy*512 + xx];
          }
        }
      corr += w2img[m*9 + k2y*3 + k2x] * y1v;
    }
  }
  for (int off = 32; off > 0; off >>= 1) corr += __shfl_down(corr, off, 64);
  if (lane == 0) ini[b*IMG + py*512 + px] -= corr;
}

// ---------------- Kernel B2: 1x1 conv on fea (+ /4) ----------------
__global__ __launch_bounds__(256) void k_feamap(const float* __restrict__ fea,
                                                const float* __restrict__ wfea,
                                                const float* __restrict__ bfea,
                                                float* __restrict__ fmap) {
  int pix = blockIdx.x * 1024 + threadIdx.x * 4;
  int b = pix >> 18;
  int rem = pix & (IMG - 1);
  const float* src = fea + (size_t)(b * 64) * IMG + rem;
  float4 acc = {0.f, 0.f, 0.f, 0.f};
  for (int c = 0; c < 64; ++c) {
    float w = wfea[c];
    float4 v = *(const float4*)(src + (size_t)c * IMG);
    acc.x += w * v.x; acc.y += w * v.y; acc.z += w * v.z; acc.w += w * v.w;
  }
  float bb = bfea[0];
  acc.x = (acc.x + bb) * 0.25f;
  acc.y = (acc.y + bb) * 0.25f;
  acc.z = (acc.z + bb) * 0.25f;
  acc.w = (acc.w + bb) * 0.25f;
  *(float4*)(fmap + pix) = acc;
}

// ---------------- Kernel C: unfold + fused linear + relu ----------------
__global__ __launch_bounds__(256) void k_trans(float* __restrict__ ws) {
  __shared__ float Us[4][64];
  __shared__ float Wt[4096];
  int bid = blockIdx.x;
  int s  = bid >> 12;
  int b  = (bid >> 10) & 3;
  int pg = bid & 1023;
  int tid = threadIdx.x;
  const float* src = ws + (s ? OFF_FMAP : OFF_INI) + b * IMG;
  float*       dst = ws + (s ? OFF_VFEA : OFF_VIMG) + b * (NPAT * 64);
  for (int idx = tid; idx < 4096; idx += 256) Wt[idx] = ws[OFF_W + idx];
  int pl = tid >> 6, j = tid & 63;
  int l  = pg * 4 + pl;
  int py = l >> 6, px = l & 63;
  Us[pl][j] = src[(py*8 + (j >> 3))*512 + px*8 + (j & 7)];
  __syncthreads();
  float acc = 0.f;
  #pragma unroll
  for (int q = 0; q < 64; ++q) acc += Us[pl][q] * Wt[q*64 + j];
  dst[l*64 + j] = fmaxf(acc, 0.f);
}

// ---------------- Kernel D: att = v_img @ v_fea^T / 64 ----------------
__global__ __launch_bounds__(256) void k_att(const float* __restrict__ ws,
                                             float* __restrict__ out) {
  __shared__ float As[64][68];
  __shared__ float Bs[64][68];
  int bid = blockIdx.x;
  int b = bid >> 12;
  int t = bid & 4095;
  int tl = t >> 6, tm = t & 63;
  int l0 = tl << 6, m0 = tm << 6;
  int tid = threadIdx.x;
  const float* va = ws + OFF_VIMG + b*(NPAT*64) + l0*64;
  const float* vb = ws + OFF_VFEA + b*(NPAT*64) + m0*64;
  #pragma unroll
  for (int i = 0; i < 4; ++i) {
    int idx = i*1024 + tid*4;
    int r = idx >> 6, j = idx & 63;
    *(float4*)&As[r][j] = *(const float4*)(va + r*64 + j);
    *(float4*)&Bs[r][j] = *(const float4*)(vb + r*64 + j);
  }
  __syncthreads();
  int tx = tid & 15, ty = tid >> 4;
  float acc[4][4] = {};
  #pragma unroll
  for (int k = 0; k < 64; ++k) {
    float a[4], bb[4];
    #pragma unroll
    for (int il = 0; il < 4; ++il) a[il] = As[ty + 16*il][k];
    #pragma unroll
    for (int im = 0; im < 4; ++im) bb[im] = Bs[tx + 16*im][k];
    #pragma unroll
    for (int il = 0; il < 4; ++il)
      #pragma unroll
      for (int im = 0; im < 4; ++im)
        acc[il][im] += a[il] * bb[im];
  }
  float* o = out + (size_t)b * 16777216 + (size_t)l0 * 4096 + m0;
  #pragma unroll
  for (int il = 0; il < 4; ++il)
    #pragma unroll
    for (int im = 0; im < 4; ++im)
      o[(ty + 16*il)*4096 + tx + 16*im] = acc[il][im] * 0.015625f;
}

extern "C" void kernel_launch(void* const* d_in, const int* in_sizes, int n_in,
                              void* d_out, int out_size, void* d_ws, size_t ws_size,
                              hipStream_t stream) {
  const float* x      = (const float*)d_in[0];
  const float* fea    = (const float*)d_in[1];
  const float* w_img1 = (const float*)d_in[2];
  const float* b_img1 = (const float*)d_in[3];
  const float* w_img2 = (const float*)d_in[4];
  const float* b_img2 = (const float*)d_in[5];
  const float* w_fea  = (const float*)d_in[6];
  const float* b_fea  = (const float*)d_in[7];
  const float* w1     = (const float*)d_in[8];
  const float* w2     = (const float*)d_in[9];
  float* ws  = (float*)d_ws;
  float* out = (float*)d_out;

  k_compose<<<1,    256, 0, stream>>>(w_img1, b_img1, w_img2, b_img2, w1, w2, ws);
  k_conv9  <<<4096, 256, 0, stream>>>(x, ws, ws + OFF_INI);
  k_ring   <<<2044, 256, 0, stream>>>(x, w_img1, b_img1, w_img2, ws + OFF_INI);
  k_feamap <<<1024, 256, 0, stream>>>(fea, w_fea, b_fea, ws + OFF_FMAP);
  k_trans  <<<8192, 256, 0, stream>>>(ws);
  k_att    <<<16384,256, 0, stream>>>(ws, out);
}

// Round 2
// 702.154 us; speedup vs baseline: 1.2128x; 1.2128x over previous
//
#include <hip/hip_runtime.h>

#define IMG  262144
#define NPAT 4096

// ws layout (float offsets)
#define OFF_C9   0                       // 243 weights + bias at [243]
#define OFF_W    256                     // Wt[q][j], 4096 floats
#define OFF_INI  4352                    // ini_img [4][512][512]
#define OFF_FMAP (OFF_INI + 4*IMG)       // feamap  [4][512][512]
#define OFF_V    (OFF_FMAP + 4*IMG)      // 4 ushort arrays of [4][4096][64]: imgH imgL feaH feaL

typedef short v8s __attribute__((ext_vector_type(8)));
typedef float v4f __attribute__((ext_vector_type(4)));

__device__ inline unsigned short f2bf(float x) {
  unsigned u = __float_as_uint(x);
  u = u + 0x7FFF + ((u >> 16) & 1);
  return (unsigned short)(u >> 16);
}
__device__ inline float bf2f(unsigned short h) {
  return __uint_as_float(((unsigned)h) << 16);
}

// ---------------- Kernel A: compose weights (17 blocks) ----------------
__global__ __launch_bounds__(256) void k_compose(
    const float* __restrict__ w1img, const float* __restrict__ b1img,
    const float* __restrict__ w2img, const float* __restrict__ b2img,
    const float* __restrict__ w1,    const float* __restrict__ w2,
    float* __restrict__ ws) {
  int bid = blockIdx.x, tid = threadIdx.x;
  if (bid < 16) {
    // Wt[q][j] = sum_k w2[j,k]*w1[k,q]; wave-uniform j -> w2 row via s_load
    int j = bid * 4 + (tid >> 6), q = tid & 63;
    float acc = 0.f;
    for (int k = 0; k < 128; ++k) acc += w2[j * 128 + k] * w1[k * 64 + q];
    ws[OFF_W + q * 64 + j] = acc;
    return;
  }
  // block 16: combined 9x9 conv weights + bias
  if (tid < 243) {
    int i = tid / 81, r = tid % 81, dy = r / 9, dx = r % 9;
    float acc = 0.f;
    for (int m = 0; m < 64; ++m)
      for (int ky = 0; ky < 3; ++ky) {
        int k1y = dy - ky; if (k1y < 0 || k1y > 6) continue;
        for (int kx = 0; kx < 3; ++kx) {
          int k1x = dx - kx; if (k1x < 0 || k1x > 6) continue;
          acc += w2img[m * 9 + ky * 3 + kx] * w1img[(m * 3 + i) * 49 + k1y * 7 + k1x];
        }
      }
    ws[OFF_C9 + tid] = acc;
  } else if (tid == 243) {
    float acc = b2img[0];
    for (int m = 0; m < 64; ++m) {
      float s = 0.f;
      for (int k = 0; k < 9; ++k) s += w2img[m * 9 + k];
      acc += b1img[m] * s;
    }
    ws[OFF_C9 + 243] = acc;
  }
}

// ---------------- Kernel B1: composite 9x9 conv (tile 16x64, 4 out/thread) ----------------
__global__ __launch_bounds__(256) void k_conv9(const float* __restrict__ x,
                                               const float* __restrict__ ws,
                                               float* __restrict__ ini) {
  __shared__ float sIn[3][24][72];
  int bid = blockIdx.x, tid = threadIdx.x;
  int b = bid >> 8, t = bid & 255;
  int ty0 = (t >> 3) << 4, tx0 = (t & 7) << 6;
  // stage 3ch x 24 x 72 halo tile
  for (int idx = tid; idx < 3 * 24 * 72; idx += 256) {
    int c = idx / 1728, r = (idx % 1728) / 72, cc = idx % 72;
    int gy = ty0 + r - 4, gx = tx0 + cc - 4;
    float v = 0.f;
    if ((unsigned)gy < 512u && (unsigned)gx < 512u)
      v = x[(b * 3 + c) * IMG + gy * 512 + gx];
    sIn[c][r][cc] = v;
  }
  __syncthreads();
  const float* Cw = ws + OFF_C9;   // uniform -> scalar loads
  int ty = tid >> 4, tx = (tid & 15) << 2;
  float bc = Cw[243];
  float a0 = bc, a1 = bc, a2 = bc, a3 = bc;
  #pragma unroll
  for (int i = 0; i < 3; ++i)
    #pragma unroll
    for (int dy = 0; dy < 9; ++dy) {
      const float* rowp = &sIn[i][ty + dy][tx];
      float4 r0 = *(const float4*)rowp;
      float4 r1 = *(const float4*)(rowp + 4);
      float4 r2 = *(const float4*)(rowp + 8);
      float tt[12] = {r0.x, r0.y, r0.z, r0.w, r1.x, r1.y, r1.z, r1.w,
                      r2.x, r2.y, r2.z, r2.w};
      #pragma unroll
      for (int dx = 0; dx < 9; ++dx) {
        float w = Cw[i * 81 + dy * 9 + dx];
        a0 += w * tt[dx];     a1 += w * tt[dx + 1];
        a2 += w * tt[dx + 2]; a3 += w * tt[dx + 3];
      }
    }
  float4 o = {a0, a1, a2, a3};
  *(float4*)&ini[b * IMG + (ty0 + ty) * 512 + tx0 + tx] = o;
}

// ---------------- Kernel B1b: border-ring correction ----------------
__global__ __launch_bounds__(256) void k_ring(const float* __restrict__ x,
                                              const float* __restrict__ w1img,
                                              const float* __restrict__ b1img,
                                              const float* __restrict__ w2img,
                                              float* __restrict__ ini) {
  int wid = blockIdx.x * 4 + (threadIdx.x >> 6);
  int lane = threadIdx.x & 63;
  int b = wid / 2044;
  int r = wid % 2044;
  int py, px;
  if (r < 512)       { py = 0;            px = r;        }
  else if (r < 1024) { py = 511;          px = r - 512;  }
  else if (r < 1534) { py = r - 1024 + 1; px = 0;        }
  else               { py = r - 1534 + 1; px = 511;      }
  int m = lane;
  float corr = 0.f;
  for (int k2y = 0; k2y < 3; ++k2y) {
    int qy = py + k2y - 1;
    for (int k2x = 0; k2x < 3; ++k2x) {
      int qx = px + k2x - 1;
      if (!(qy < 0 || qy >= 512 || qx < 0 || qx >= 512)) continue;
      float y1v = b1img[m];
      for (int i = 0; i < 3; ++i)
        for (int k1y = 0; k1y < 7; ++k1y) {
          int xy = qy + k1y - 3;
          if (xy < 0 || xy >= 512) continue;
          for (int k1x = 0; k1x < 7; ++k1x) {
            int xx = qx + k1x - 3;
            if (xx < 0 || xx >= 512) continue;
            y1v += w1img[(m * 3 + i) * 49 + k1y * 7 + k1x] * x[(b * 3 + i) * IMG + xy * 512 + xx];
          }
        }
      corr += w2img[m * 9 + k2y * 3 + k2x] * y1v;
    }
  }
  for (int off = 32; off > 0; off >>= 1) corr += __shfl_down(corr, off, 64);
  if (lane == 0) ini[b * IMG + py * 512 + px] -= corr;
}

// ---------------- Kernel B2: 1x1 conv on fea (+ /4) ----------------
__global__ __launch_bounds__(256) void k_feamap(const float* __restrict__ fea,
                                                const float* __restrict__ wfea,
                                                const float* __restrict__ bfea,
                                                float* __restrict__ fmap) {
  int pix = blockIdx.x * 1024 + threadIdx.x * 4;
  int b = pix >> 18;
  int rem = pix & (IMG - 1);
  const float* src = fea + (size_t)(b * 64) * IMG + rem;
  float4 acc = {0.f, 0.f, 0.f, 0.f};
  for (int c = 0; c < 64; ++c) {
    float w = wfea[c];
    float4 v = *(const float4*)(src + (size_t)c * IMG);
    acc.x += w * v.x; acc.y += w * v.y; acc.z += w * v.z; acc.w += w * v.w;
  }
  float bb = bfea[0];
  acc.x = (acc.x + bb) * 0.25f;
  acc.y = (acc.y + bb) * 0.25f;
  acc.z = (acc.z + bb) * 0.25f;
  acc.w = (acc.w + bb) * 0.25f;
  *(float4*)(fmap + pix) = acc;
}

// ---------------- Kernel C: unfold + fused linear + relu + bf16 hi/lo split ----------------
__global__ __launch_bounds__(256) void k_trans(float* __restrict__ ws) {
  __shared__ float Us[64][68];
  int bid = blockIdx.x, tid = threadIdx.x;
  int s = bid >> 8, b = (bid >> 6) & 3, py = bid & 63;
  const float* src = ws + (s ? OFF_FMAP : OFF_INI) + b * IMG + py * 8 * 512;
  unsigned short* Vh = (unsigned short*)(ws + OFF_V) + (s ? 2097152 : 0) + b * NPAT * 64;
  unsigned short* Vl = Vh + 1048576;
  // stage 8 rows x 512 cols -> Us[px][q]  (q = r*8+c)
  #pragma unroll
  for (int i = 0; i < 4; ++i) {
    int idx = tid + 256 * i;          // 0..1023 float4 slots
    int row = idx >> 7;               // 0..7
    int c4  = (idx & 127) * 4;        // 0..508
    float4 v = *(const float4*)(src + row * 512 + c4);
    int px = c4 >> 3, c = c4 & 7;
    *(float4*)&Us[px][row * 8 + c] = v;
  }
  int j = tid & 63, wid = tid >> 6;
  float wc[64];
  #pragma unroll
  for (int q = 0; q < 64; ++q) wc[q] = ws[OFF_W + q * 64 + j];
  __syncthreads();
  #pragma unroll
  for (int i = 0; i < 16; ++i) {
    int lp = wid * 16 + i;
    float acc = 0.f;
    #pragma unroll
    for (int q4 = 0; q4 < 16; ++q4) {
      float4 u = *(const float4*)&Us[lp][q4 * 4];
      acc += u.x * wc[4*q4] + u.y * wc[4*q4+1] + u.z * wc[4*q4+2] + u.w * wc[4*q4+3];
    }
    acc = fmaxf(acc, 0.f);
    unsigned short h = f2bf(acc);
    unsigned short lo = f2bf(acc - bf2f(h));
    int lg = py * 64 + lp;
    Vh[lg * 64 + j] = h;
    Vl[lg * 64 + j] = lo;
  }
}

// ---------------- Kernel D: att = v_img @ v_fea^T / 64  (bf16-split MFMA) ----------------
__global__ __launch_bounds__(256) void k_att(const float* __restrict__ ws,
                                             float* __restrict__ out) {
  __shared__ unsigned short lds[4][128][64];  // Ah Al Bh Bl, XOR-swizzled 16B segs
  int bid = blockIdx.x, tid = threadIdx.x;
  int b = bid >> 10, t = bid & 1023;
  int l0 = (t >> 5) << 7, m0 = (t & 31) << 7;
  const unsigned short* V = (const unsigned short*)(ws + OFF_V);
  const unsigned short* pA_h = V + (b * NPAT + l0) * 64;
  const unsigned short* pA_l = V + 1048576 + (b * NPAT + l0) * 64;
  const unsigned short* pB_h = V + 2097152 + (b * NPAT + m0) * 64;
  const unsigned short* pB_l = V + 3145728 + (b * NPAT + m0) * 64;
  #pragma unroll
  for (int i = 0; i < 4; ++i) {
    int idx = tid + 256 * i;            // 0..1023: row(128) x seg(8)
    int row = idx >> 3, sg = idx & 7;
    int p = (sg ^ (row & 7)) * 8;
    *(uint4*)&lds[0][row][p] = *(const uint4*)(pA_h + row * 64 + sg * 8);
    *(uint4*)&lds[1][row][p] = *(const uint4*)(pA_l + row * 64 + sg * 8);
    *(uint4*)&lds[2][row][p] = *(const uint4*)(pB_h + row * 64 + sg * 8);
    *(uint4*)&lds[3][row][p] = *(const uint4*)(pB_l + row * 64 + sg * 8);
  }
  __syncthreads();
  int lane = tid & 63, wid = tid >> 6;
  int wm = (wid & 1) << 6, wn = (wid >> 1) << 6;
  int mlo = lane & 15, quad = lane >> 4;
  v4f acc[4][4] = {};
  #pragma unroll
  for (int kh = 0; kh < 2; ++kh) {
    int sL = quad + 4 * kh;
    v8s ah[4], al[4], bh[4], bl[4];
    #pragma unroll
    for (int mi = 0; mi < 4; ++mi) {
      int r = wm + mi * 16 + mlo;
      int p = (sL ^ (r & 7)) * 8;
      ah[mi] = *(const v8s*)&lds[0][r][p];
      al[mi] = *(const v8s*)&lds[1][r][p];
    }
    #pragma unroll
    for (int ni = 0; ni < 4; ++ni) {
      int r = wn + ni * 16 + mlo;
      int p = (sL ^ (r & 7)) * 8;
      bh[ni] = *(const v8s*)&lds[2][r][p];
      bl[ni] = *(const v8s*)&lds[3][r][p];
    }
    #pragma unroll
    for (int mi = 0; mi < 4; ++mi)
      #pragma unroll
      for (int ni = 0; ni < 4; ++ni) {
        acc[mi][ni] = __builtin_amdgcn_mfma_f32_16x16x32_bf16(ah[mi], bh[ni], acc[mi][ni], 0, 0, 0);
        acc[mi][ni] = __builtin_amdgcn_mfma_f32_16x16x32_bf16(ah[mi], bl[ni], acc[mi][ni], 0, 0, 0);
        acc[mi][ni] = __builtin_amdgcn_mfma_f32_16x16x32_bf16(al[mi], bh[ni], acc[mi][ni], 0, 0, 0);
      }
  }
  float* o = out + (size_t)b * 16777216;
  #pragma unroll
  for (int mi = 0; mi < 4; ++mi)
    #pragma unroll
    for (int ni = 0; ni < 4; ++ni) {
      int col = m0 + wn + ni * 16 + mlo;
      #pragma unroll
      for (int rr = 0; rr < 4; ++rr) {
        int row = l0 + wm + mi * 16 + quad * 4 + rr;
        o[(size_t)row * 4096 + col] = acc[mi][ni][rr] * 0.015625f;
      }
    }
}

extern "C" void kernel_launch(void* const* d_in, const int* in_sizes, int n_in,
                              void* d_out, int out_size, void* d_ws, size_t ws_size,
                              hipStream_t stream) {
  const float* x      = (const float*)d_in[0];
  const float* fea    = (const float*)d_in[1];
  const float* w_img1 = (const float*)d_in[2];
  const float* b_img1 = (const float*)d_in[3];
  const float* w_img2 = (const float*)d_in[4];
  const float* b_img2 = (const float*)d_in[5];
  const float* w_fea  = (const float*)d_in[6];
  const float* b_fea  = (const float*)d_in[7];
  const float* w1     = (const float*)d_in[8];
  const float* w2     = (const float*)d_in[9];
  float* ws  = (float*)d_ws;
  float* out = (float*)d_out;

  k_compose<<<17,   256, 0, stream>>>(w_img1, b_img1, w_img2, b_img2, w1, w2, ws);
  k_conv9  <<<1024, 256, 0, stream>>>(x, ws, ws + OFF_INI);
  k_ring   <<<2044, 256, 0, stream>>>(x, w_img1, b_img1, w_img2, ws + OFF_INI);
  k_feamap <<<1024, 256, 0, stream>>>(fea, w_fea, b_fea, ws + OFF_FMAP);
  k_trans  <<<512,  256, 0, stream>>>(ws);
  k_att    <<<4096, 256, 0, stream>>>(ws, out);
}